// Round 21
// baseline (118.034 us; speedup 1.0000x reference)
//
#include <hip/hip_runtime.h>

#define D 64          // D_IN == D_OUT == 64
#define CAP 48        // payload slots per destination (avg degree 16)
#define OVCAP 131072  // overflow list capacity

typedef unsigned short ushort_t;
typedef __attribute__((ext_vector_type(8))) short bf16x8;
typedef __attribute__((ext_vector_type(4))) float f32x4;

__device__ __forceinline__ void fma4(float4& c, float a, const float4& b) {
  c.x = fmaf(a, b.x, c.x);
  c.y = fmaf(a, b.y, c.y);
  c.z = fmaf(a, b.z, c.z);
  c.w = fmaf(a, b.w, c.w);
}

__device__ __forceinline__ unsigned short f2bf(float f) {  // RNE pack
  unsigned u = __float_as_uint(f);
  return (unsigned short)((u + 0x7FFFu + ((u >> 16) & 1u)) >> 16);
}
__device__ __forceinline__ float bf2f(unsigned short h) {
  return __uint_as_float((unsigned)h << 16);
}
__device__ __forceinline__ unsigned pk2(float a, float b) {
  return (unsigned)f2bf(a) | ((unsigned)f2bf(b) << 16);
}

__device__ __forceinline__ bf16x8 pack_bf8(float4 v0, float4 v1) {
  bf16x8 r;
  r[0] = (short)f2bf(v0.x); r[1] = (short)f2bf(v0.y);
  r[2] = (short)f2bf(v0.z); r[3] = (short)f2bf(v0.w);
  r[4] = (short)f2bf(v1.x); r[5] = (short)f2bf(v1.y);
  r[6] = (short)f2bf(v1.z); r[7] = (short)f2bf(v1.w);
  return r;
}

// ---------------- K1: prep = W transpose (blocks 0..R) || zero deg/ovcnt ----------------
__global__ void prep(const float* __restrict__ weight, const float* __restrict__ loopw,
                     ushort_t* __restrict__ Wt, int* __restrict__ deg,
                     int* __restrict__ ovcnt, int R, int N) {
  if ((int)blockIdx.x <= R) {
    const int m = blockIdx.x;
    const float* W = (m < R) ? weight + (size_t)m * D * D : loopw;
    ushort_t* o = Wt + (size_t)m * D * D;
    for (int i = threadIdx.x; i < 1024; i += 256) {
      float4 v = ((const float4*)W)[i];
      int k = i >> 4;
      int c = (i & 15) * 4;
      o[(c + 0) * D + k] = f2bf(v.x);
      o[(c + 1) * D + k] = f2bf(v.y);
      o[(c + 2) * D + k] = f2bf(v.z);
      o[(c + 3) * D + k] = f2bf(v.w);
    }
    if (blockIdx.x == 0 && threadIdx.x == 0) *ovcnt = 0;
  } else {
    int i = (blockIdx.x - (R + 1)) * 256 + threadIdx.x;
    if (i < N) deg[i] = 0;
  }
}

// ---------------- proj body (R13-proven: 16 nodes/wave, node-major tiled layout) ----------------
// Tiled col permutation: storage 16g+4ct+r <-> actual col 16ct+4g+r.
template <int NM>   // NM = R+1, compile-time
__device__ __forceinline__ void proj_body(const float* __restrict__ feat,
                                          const ushort_t* __restrict__ Wt,
                                          ushort_t* __restrict__ proj,
                                          float* __restrict__ out, int N, int blk) {
  const int t = threadIdx.x;
  const int lane = t & 63;
  const int wid = t >> 6;
  const int node = blk * 64 + wid * 16 + (lane & 15);
  const int g = lane >> 4;
  const int kb = g * 8;
  const int R8 = NM - 1;

  bf16x8 b0, b1;
  {
    float4 v0 = make_float4(0.f, 0.f, 0.f, 0.f), v1 = v0, v2 = v0, v3 = v0;
    if (node < N) {
      const float* p = feat + (size_t)node * D + kb;
      v0 = *(const float4*)p;
      v1 = *(const float4*)(p + 4);
      v2 = *(const float4*)(p + 32);
      v3 = *(const float4*)(p + 36);
    }
    b0 = pack_bf8(v0, v1);
    b1 = pack_bf8(v2, v3);
  }

#pragma unroll 2
  for (int m = 0; m < NM; ++m) {
    const ushort_t* wt = Wt + (size_t)m * D * D + kb;
    f32x4 acc[4];
#pragma unroll
    for (int ct = 0; ct < 4; ++ct) {
      const ushort_t* wr = wt + (size_t)(16 * ct + (lane & 15)) * D;
      bf16x8 a0 = *(const bf16x8*)wr;
      bf16x8 a1 = *(const bf16x8*)(wr + 32);
      acc[ct] = (f32x4){0.f, 0.f, 0.f, 0.f};
      acc[ct] = __builtin_amdgcn_mfma_f32_16x16x32_bf16(a0, b0, acc[ct], 0, 0, 0);
      acc[ct] = __builtin_amdgcn_mfma_f32_16x16x32_bf16(a1, b1, acc[ct], 0, 0, 0);
    }
    if (node < N) {
      if (m < R8) {
        ushort_t* op = proj + ((size_t)node * R8 + m) * D + 16 * g;
        uint4 w0, w1;
        w0.x = pk2(acc[0][0], acc[0][1]); w0.y = pk2(acc[0][2], acc[0][3]);
        w0.z = pk2(acc[1][0], acc[1][1]); w0.w = pk2(acc[1][2], acc[1][3]);
        w1.x = pk2(acc[2][0], acc[2][1]); w1.y = pk2(acc[2][2], acc[2][3]);
        w1.z = pk2(acc[3][0], acc[3][1]); w1.w = pk2(acc[3][2], acc[3][3]);
        *(uint4*)(op) = w0;
        *(uint4*)(op + 8) = w1;
      } else {
        float* op = out + (size_t)node * D + 4 * g;   // canonical
#pragma unroll
        for (int ct = 0; ct < 4; ++ct) {
          float4 v;
          v.x = acc[ct][0]; v.y = acc[ct][1]; v.z = acc[ct][2]; v.w = acc[ct][3];
          *(float4*)(op + 16 * ct) = v;
        }
      }
    }
  }
}

// Runtime-R variant.
__device__ __forceinline__ void proj_body_rt(const float* __restrict__ feat,
                                             const ushort_t* __restrict__ Wt,
                                             ushort_t* __restrict__ proj,
                                             float* __restrict__ out, int N, int R,
                                             int blk) {
  const int t = threadIdx.x;
  const int lane = t & 63;
  const int wid = t >> 6;
  const int node = blk * 64 + wid * 16 + (lane & 15);
  const int g = lane >> 4;
  const int kb = g * 8;

  bf16x8 b0, b1;
  {
    float4 v0 = make_float4(0.f, 0.f, 0.f, 0.f), v1 = v0, v2 = v0, v3 = v0;
    if (node < N) {
      const float* p = feat + (size_t)node * D + kb;
      v0 = *(const float4*)p;
      v1 = *(const float4*)(p + 4);
      v2 = *(const float4*)(p + 32);
      v3 = *(const float4*)(p + 36);
    }
    b0 = pack_bf8(v0, v1);
    b1 = pack_bf8(v2, v3);
  }

  for (int m = 0; m <= R; ++m) {
    const ushort_t* wt = Wt + (size_t)m * D * D + kb;
    f32x4 acc[4];
#pragma unroll
    for (int ct = 0; ct < 4; ++ct) {
      const ushort_t* wr = wt + (size_t)(16 * ct + (lane & 15)) * D;
      bf16x8 a0 = *(const bf16x8*)wr;
      bf16x8 a1 = *(const bf16x8*)(wr + 32);
      acc[ct] = (f32x4){0.f, 0.f, 0.f, 0.f};
      acc[ct] = __builtin_amdgcn_mfma_f32_16x16x32_bf16(a0, b0, acc[ct], 0, 0, 0);
      acc[ct] = __builtin_amdgcn_mfma_f32_16x16x32_bf16(a1, b1, acc[ct], 0, 0, 0);
    }
    if (node < N) {
      if (m < R) {
        ushort_t* op = proj + ((size_t)node * R + m) * D + 16 * g;
        uint4 w0, w1;
        w0.x = pk2(acc[0][0], acc[0][1]); w0.y = pk2(acc[0][2], acc[0][3]);
        w0.z = pk2(acc[1][0], acc[1][1]); w0.w = pk2(acc[1][2], acc[1][3]);
        w1.x = pk2(acc[2][0], acc[2][1]); w1.y = pk2(acc[2][2], acc[2][3]);
        w1.z = pk2(acc[3][0], acc[3][1]); w1.w = pk2(acc[3][2], acc[3][3]);
        *(uint4*)(op) = w0;
        *(uint4*)(op + 8) = w1;
      } else {
        float* op = out + (size_t)node * D + 4 * g;
#pragma unroll
        for (int ct = 0; ct < 4; ++ct) {
          float4 v;
          v.x = acc[ct][0]; v.y = acc[ct][1]; v.z = acc[ct][2]; v.w = acc[ct][3];
          *(float4*)(op + 16 * ct) = v;
        }
      }
    }
  }
}

// Fused rank+scatter, 16 edges/thread: 16 independent atomic returns in flight,
// then 16 batched scattered stores.
__device__ __forceinline__ void scat16_body(const int* __restrict__ esrc,
                                            const int* __restrict__ edst,
                                            const int* __restrict__ etype,
                                            const float* __restrict__ att,
                                            int* __restrict__ deg,
                                            int2* __restrict__ payload,
                                            int* __restrict__ ovcnt,
                                            int4* __restrict__ ovlist,
                                            int E, int sblk) {
  const int base = (sblk * 256 + (int)threadIdx.x) * 16;
  if (base + 15 < E) {
    int4 s[4], d[4], ty[4];
    float4 a[4];
    int rk[16];
#pragma unroll
    for (int j = 0; j < 4; ++j) {
      s[j]  = *(const int4*)(esrc + base + 4 * j);
      d[j]  = *(const int4*)(edst + base + 4 * j);
      ty[j] = *(const int4*)(etype + base + 4 * j);
      a[j]  = *(const float4*)(att + base + 4 * j);
    }
#pragma unroll
    for (int j = 0; j < 4; ++j) {
      rk[4 * j + 0] = atomicAdd(&deg[d[j].x], 1);
      rk[4 * j + 1] = atomicAdd(&deg[d[j].y], 1);
      rk[4 * j + 2] = atomicAdd(&deg[d[j].z], 1);
      rk[4 * j + 3] = atomicAdd(&deg[d[j].w], 1);
    }
#define EMIT(dn, sv, tv, av, r)                                                      \
    {                                                                                \
      int2 pay = make_int2((sv) | ((tv) << 24), __float_as_int(av));                 \
      if ((r) < CAP) payload[(size_t)(dn) * CAP + (r)] = pay;                        \
      else { int ov = atomicAdd(ovcnt, 1);                                           \
             if (ov < OVCAP) ovlist[ov] = make_int4(pay.x, pay.y, (dn), 0); }        \
    }
#pragma unroll
    for (int j = 0; j < 4; ++j) {
      EMIT(d[j].x, s[j].x, ty[j].x, a[j].x, rk[4 * j + 0])
      EMIT(d[j].y, s[j].y, ty[j].y, a[j].y, rk[4 * j + 1])
      EMIT(d[j].z, s[j].z, ty[j].z, a[j].z, rk[4 * j + 2])
      EMIT(d[j].w, s[j].w, ty[j].w, a[j].w, rk[4 * j + 3])
    }
#undef EMIT
  } else {
    for (int i = base; i < E; ++i) {
      int dn = edst[i];
      int r = atomicAdd(&deg[dn], 1);
      int2 pay = make_int2(esrc[i] | (etype[i] << 24), __float_as_int(att[i]));
      if (r < CAP) payload[(size_t)dn * CAP + r] = pay;
      else { int ov = atomicAdd(ovcnt, 1); if (ov < OVCAP) ovlist[ov] = make_int4(pay.x, pay.y, dn, 0); }
    }
  }
}

// K2 (R13-proven spatial role partition): blocks [0,PB) proj, [PB,PB+SB) scat16.
__global__ __launch_bounds__(256) void proj_scat(const float* __restrict__ feat,
                                                 const ushort_t* __restrict__ Wt,
                                                 ushort_t* __restrict__ proj,
                                                 float* __restrict__ out,
                                                 const int* __restrict__ esrc,
                                                 const int* __restrict__ edst,
                                                 const int* __restrict__ etype,
                                                 const float* __restrict__ att,
                                                 int* __restrict__ deg,
                                                 int2* __restrict__ payload,
                                                 int* __restrict__ ovcnt,
                                                 int4* __restrict__ ovlist,
                                                 int N, int E, int R, int PB) {
  if ((int)blockIdx.x < PB) {
    if (R == 8)
      proj_body<9>(feat, Wt, proj, out, N, blockIdx.x);
    else
      proj_body_rt(feat, Wt, proj, out, N, R, blockIdx.x);
  } else {
    scat16_body(esrc, edst, etype, att, deg, payload, ovcnt, ovlist, E,
                blockIdx.x - PB);
  }
}

// ---------------- K3: node gather (paired slot loads) || overflow fixup ----------------
__global__ __launch_bounds__(256, 8) void gather_fix(const int* __restrict__ deg,
                                                     const int2* __restrict__ payload,
                                                     const ushort_t* __restrict__ proj,
                                                     const float* __restrict__ hbias,
                                                     float* __restrict__ out, int N,
                                                     int R, int GB,
                                                     const int* __restrict__ ovcnt,
                                                     const int4* __restrict__ ovlist) {
  if ((int)blockIdx.x < GB) {
    const int n = ((int)blockIdx.x * 256 + (int)threadIdx.x) >> 6;
    if (n >= N) return;
    const int lane = threadIdx.x & 63;
    const int sub = lane >> 4;
    const int q = lane & 15;
    const int ac0 = 16 * (q & 3) + 4 * (q >> 2);   // actual col base for chunk q

    const int cnt = min(deg[n], CAP);
    const int2* slots = payload + (size_t)n * CAP;
    float4 acc = make_float4(0.f, 0.f, 0.f, 0.f);
    float sa = 0.f;
    // Each sub owns slot pairs {2s, 2s+1} stride 8: one int4 load = 2 payloads.
    for (int e = sub * 2; e < cnt; e += 8) {
      const int4 pp = *(const int4*)(slots + e);   // slots[e], slots[e+1]
      {
        const float a = __int_as_float(pp.y);
        const int src = pp.x & 0x00FFFFFF;
        const int r = ((unsigned)pp.x) >> 24;
        const ushort4 p = *(const ushort4*)(proj + ((size_t)src * R + r) * D + q * 4);
        acc.x = fmaf(a, bf2f(p.x), acc.x);
        acc.y = fmaf(a, bf2f(p.y), acc.y);
        acc.z = fmaf(a, bf2f(p.z), acc.z);
        acc.w = fmaf(a, bf2f(p.w), acc.w);
        sa += a;
      }
      if (e + 1 < cnt) {
        const float a = __int_as_float(pp.w);
        const int src = pp.z & 0x00FFFFFF;
        const int r = ((unsigned)pp.z) >> 24;
        const ushort4 p = *(const ushort4*)(proj + ((size_t)src * R + r) * D + q * 4);
        acc.x = fmaf(a, bf2f(p.x), acc.x);
        acc.y = fmaf(a, bf2f(p.y), acc.y);
        acc.z = fmaf(a, bf2f(p.z), acc.z);
        acc.w = fmaf(a, bf2f(p.w), acc.w);
        sa += a;
      }
    }
#pragma unroll
    for (int m = 16; m < 64; m <<= 1) {
      acc.x += __shfl_xor(acc.x, m);
      acc.y += __shfl_xor(acc.y, m);
      acc.z += __shfl_xor(acc.z, m);
      acc.w += __shfl_xor(acc.w, m);
      sa += __shfl_xor(sa, m);
    }
    if (sub == 0) {
      const float4 hb = *(const float4*)(hbias + ac0);
      float* op = out + (size_t)n * D + ac0;
      float4 cur = *(float4*)op;      // self-loop already there (canonical layout)
      cur.x += acc.x + sa * hb.x;
      cur.y += acc.y + sa * hb.y;
      cur.z += acc.z + sa * hb.z;
      cur.w += acc.w + sa * hb.w;
      *(float4*)op = cur;
    }
  } else {
    const int total = min(*ovcnt, OVCAP) * 16;
    for (int i = ((int)blockIdx.x - GB) * 256 + (int)threadIdx.x; i < total;
         i += 16 * 256) {
      const int idx = i >> 4, q = i & 15;
      const int4 en = ovlist[idx];
      const int src = en.x & 0x00FFFFFF;
      const int r = ((unsigned)en.x) >> 24;
      const float a = __int_as_float(en.y);
      const int ac0 = 16 * (q & 3) + 4 * (q >> 2);
      const ushort4 p = *(const ushort4*)(proj + ((size_t)src * R + r) * D + q * 4);
      const float4 hb = *(const float4*)(hbias + ac0);
      float* op = out + (size_t)en.z * D + ac0;
      unsafeAtomicAdd(op + 0, (bf2f(p.x) + hb.x) * a);
      unsafeAtomicAdd(op + 1, (bf2f(p.y) + hb.y) * a);
      unsafeAtomicAdd(op + 2, (bf2f(p.z) + hb.z) * a);
      unsafeAtomicAdd(op + 3, (bf2f(p.w) + hb.w) * a);
    }
  }
}

// ---------------- fallback path (small ws): fp32 tile GEMM + atomic scatter ----------------
__global__ __launch_bounds__(256, 3) void proj_single(const float* __restrict__ feat,
                                                      const float* __restrict__ W,
                                                      float* __restrict__ outp, int N) {
  __shared__ float sW[64 * 64];
  __shared__ float sF[64 * 132];
  const int t = threadIdx.x;
  const int tileBase = blockIdx.x * 128;

  {
    const float4* Wv = (const float4*)W;
    float4* sWv = (float4*)sW;
    for (int k = t; k < 1024; k += 256) sWv[k] = Wv[k];
  }
  {
    const int row = t >> 1, half = t & 1;
    const int gr = tileBase + row;
    if (gr < N) {
      const float4* src = (const float4*)(feat + (size_t)gr * D + half * 32);
#pragma unroll
      for (int k = 0; k < 8; ++k) {
        float4 v = src[k];
        int i0 = half * 32 + k * 4;
        sF[(i0 + 0) * 132 + row] = v.x;
        sF[(i0 + 1) * 132 + row] = v.y;
        sF[(i0 + 2) * 132 + row] = v.z;
        sF[(i0 + 3) * 132 + row] = v.w;
      }
    } else {
#pragma unroll
      for (int k = 0; k < 8; ++k) {
        int i0 = half * 32 + k * 4;
        sF[(i0 + 0) * 132 + row] = 0.f;
        sF[(i0 + 1) * 132 + row] = 0.f;
        sF[(i0 + 2) * 132 + row] = 0.f;
        sF[(i0 + 3) * 132 + row] = 0.f;
      }
    }
  }
  __syncthreads();

  const int c0 = (t & 15) * 4;
  const int r0 = (t >> 4) * 8;
  float4 acc[8];
#pragma unroll
  for (int rr = 0; rr < 8; ++rr) acc[rr] = make_float4(0.f, 0.f, 0.f, 0.f);

#pragma unroll 8
  for (int i = 0; i < 64; ++i) {
    float4 w  = *(const float4*)&sW[i * 64 + c0];
    float4 a0 = *(const float4*)&sF[i * 132 + r0];
    float4 a1 = *(const float4*)&sF[i * 132 + r0 + 4];
    fma4(acc[0], a0.x, w); fma4(acc[1], a0.y, w);
    fma4(acc[2], a0.z, w); fma4(acc[3], a0.w, w);
    fma4(acc[4], a1.x, w); fma4(acc[5], a1.y, w);
    fma4(acc[6], a1.z, w); fma4(acc[7], a1.w, w);
  }

#pragma unroll
  for (int rr = 0; rr < 8; ++rr) {
    int gn = tileBase + r0 + rr;
    if (gn < N) *(float4*)(outp + (size_t)gn * D + c0) = acc[rr];
  }
}

__global__ __launch_bounds__(256, 8) void edge_scatter(const int* __restrict__ esrc,
                                                       const int* __restrict__ edst,
                                                       const int* __restrict__ etype,
                                                       const float* __restrict__ att,
                                                       const float* __restrict__ proj,
                                                       const float* __restrict__ hbias,
                                                       float* __restrict__ out,
                                                       int E, int N, int relFilter) {
  const int t = blockIdx.x * 256 + threadIdx.x;
  const int wave = t >> 6;
  const int lane = threadIdx.x & 63;
  const int sub = lane >> 4;
  const int q = lane & 15;
  const long e = (long)wave * 4 + sub;
  if (e >= E) return;
  const int r = etype[e];
  if (relFilter >= 0 && r != relFilter) return;
  const int s = esrc[e];
  const int dn = edst[e];
  const float a = att[e];
  const size_t base = (size_t)s * D;
  const float4 hb = ((const float4*)hbias)[q];
  const float4 p = *(const float4*)(proj + base + q * 4);
  float* op = out + (size_t)dn * D + q * 4;
  unsafeAtomicAdd(op + 0, (p.x + hb.x) * a);
  unsafeAtomicAdd(op + 1, (p.y + hb.y) * a);
  unsafeAtomicAdd(op + 2, (p.z + hb.z) * a);
  unsafeAtomicAdd(op + 3, (p.w + hb.w) * a);
}

extern "C" void kernel_launch(void* const* d_in, const int* in_sizes, int n_in,
                              void* d_out, int out_size, void* d_ws, size_t ws_size,
                              hipStream_t stream) {
  const float* feat   = (const float*)d_in[0];
  const int* esrc     = (const int*)d_in[1];
  const int* edst     = (const int*)d_in[2];
  const int* etype    = (const int*)d_in[3];
  const float* att    = (const float*)d_in[4];
  const float* weight = (const float*)d_in[5];
  const float* hbias  = (const float*)d_in[6];
  const float* loopw  = (const float*)d_in[7];
  float* out = (float*)d_out;

  const int N = in_sizes[0] / D;          // 50000
  const int E = in_sizes[1];              // 800000
  const int R = in_sizes[5] / (D * D);    // 8

  const int Npad = (N + 3) & ~3;

  // Workspace: Wt | proj(bf16, node-major) | deg(Npad) | ovcnt | ovlist | payload
  const size_t wtBytes   = (size_t)(R + 1) * D * D * 2;
  const size_t projBytes = (size_t)N * R * D * 2;
  const size_t degOff    = wtBytes + projBytes;
  const size_t ovcntOff  = degOff + (size_t)Npad * 4;
  const size_t ovlistOff = (ovcntOff + 16 + 15) & ~(size_t)15;
  const size_t payOffB   = (ovlistOff + (size_t)OVCAP * 16 + 15) & ~(size_t)15;
  const size_t needSlot  = payOffB + (size_t)N * CAP * 8;

  const int PB = (N + 63) / 64;                       // proj blocks (64 nodes each)
  const int SB = ((E + 15) / 16 + 255) / 256;         // scat16 blocks (4096 edges each)
  const int GB = (N + 3) / 4;                         // gather blocks

  if (ws_size >= needSlot) {
    ushort_t* Wt   = (ushort_t*)d_ws;
    ushort_t* proj = (ushort_t*)((char*)d_ws + wtBytes);
    int* deg       = (int*)((char*)d_ws + degOff);
    int* ovcnt     = (int*)((char*)d_ws + ovcntOff);
    int4* ovlist   = (int4*)((char*)d_ws + ovlistOff);
    int2* payload  = (int2*)((char*)d_ws + payOffB);

    prep<<<(R + 1) + (N + 255) / 256, 256, 0, stream>>>(weight, loopw, Wt, deg,
                                                        ovcnt, R, N);
    proj_scat<<<PB + SB, 256, 0, stream>>>(feat, Wt, proj, out, esrc, edst, etype, att,
                                           deg, payload, ovcnt, ovlist, N, E, R, PB);
    gather_fix<<<GB + 16, 256, 0, stream>>>(deg, payload, proj, hbias, out, N, R, GB,
                                            ovcnt, ovlist);
  } else {
    // Minimal-scratch fallback: needs N*D floats.
    const int tilesN = (N + 127) / 128;
    const int eblocks16 = (E + 15) / 16;
    proj_single<<<tilesN, 256, 0, stream>>>(feat, loopw, out, N);
    for (int r = 0; r < R; ++r) {
      proj_single<<<tilesN, 256, 0, stream>>>(feat, weight + (size_t)r * D * D,
                                              (float*)d_ws, N);
      edge_scatter<<<eblocks16, 256, 0, stream>>>(esrc, edst, etype, att, (float*)d_ws,
                                                  hbias, out, E, N, r);
    }
  }
}

// Round 22
// 100.086 us; speedup vs baseline: 1.1793x; 1.1793x over previous
//
#include <hip/hip_runtime.h>

#define D 64          // D_IN == D_OUT == 64
#define CAP 48        // payload slots per destination (avg degree 16)
#define OVCAP 131072  // overflow list capacity

typedef unsigned short ushort_t;
typedef __attribute__((ext_vector_type(8))) short bf16x8;
typedef __attribute__((ext_vector_type(4))) float f32x4;

__device__ __forceinline__ void fma4(float4& c, float a, const float4& b) {
  c.x = fmaf(a, b.x, c.x);
  c.y = fmaf(a, b.y, c.y);
  c.z = fmaf(a, b.z, c.z);
  c.w = fmaf(a, b.w, c.w);
}

__device__ __forceinline__ unsigned short f2bf(float f) {  // RNE pack
  unsigned u = __float_as_uint(f);
  return (unsigned short)((u + 0x7FFFu + ((u >> 16) & 1u)) >> 16);
}
__device__ __forceinline__ float bf2f(unsigned short h) {
  return __uint_as_float((unsigned)h << 16);
}
__device__ __forceinline__ unsigned pk2(float a, float b) {
  return (unsigned)f2bf(a) | ((unsigned)f2bf(b) << 16);
}

__device__ __forceinline__ bf16x8 pack_bf8(float4 v0, float4 v1) {
  bf16x8 r;
  r[0] = (short)f2bf(v0.x); r[1] = (short)f2bf(v0.y);
  r[2] = (short)f2bf(v0.z); r[3] = (short)f2bf(v0.w);
  r[4] = (short)f2bf(v1.x); r[5] = (short)f2bf(v1.y);
  r[6] = (short)f2bf(v1.z); r[7] = (short)f2bf(v1.w);
  return r;
}

// ---------------- K1: prep = W transpose (blocks 0..R) || zero deg/ovcnt ----------------
__global__ void prep(const float* __restrict__ weight, const float* __restrict__ loopw,
                     ushort_t* __restrict__ Wt, int* __restrict__ deg,
                     int* __restrict__ ovcnt, int R, int N) {
  if ((int)blockIdx.x <= R) {
    const int m = blockIdx.x;
    const float* W = (m < R) ? weight + (size_t)m * D * D : loopw;
    ushort_t* o = Wt + (size_t)m * D * D;
    for (int i = threadIdx.x; i < 1024; i += 256) {
      float4 v = ((const float4*)W)[i];
      int k = i >> 4;
      int c = (i & 15) * 4;
      o[(c + 0) * D + k] = f2bf(v.x);
      o[(c + 1) * D + k] = f2bf(v.y);
      o[(c + 2) * D + k] = f2bf(v.z);
      o[(c + 3) * D + k] = f2bf(v.w);
    }
    if (blockIdx.x == 0 && threadIdx.x == 0) *ovcnt = 0;
  } else {
    int i = (blockIdx.x - (R + 1)) * 256 + threadIdx.x;
    if (i < N) deg[i] = 0;
  }
}

// ---------------- proj body (R13-proven: 16 nodes/wave, node-major tiled layout) ----------------
// Tiled col permutation: storage 16g+4ct+r <-> actual col 16ct+4g+r.
template <int NM>   // NM = R+1, compile-time
__device__ __forceinline__ void proj_body(const float* __restrict__ feat,
                                          const ushort_t* __restrict__ Wt,
                                          ushort_t* __restrict__ proj,
                                          float* __restrict__ out, int N, int blk) {
  const int t = threadIdx.x;
  const int lane = t & 63;
  const int wid = t >> 6;
  const int node = blk * 64 + wid * 16 + (lane & 15);
  const int g = lane >> 4;
  const int kb = g * 8;
  const int R8 = NM - 1;

  bf16x8 b0, b1;
  {
    float4 v0 = make_float4(0.f, 0.f, 0.f, 0.f), v1 = v0, v2 = v0, v3 = v0;
    if (node < N) {
      const float* p = feat + (size_t)node * D + kb;
      v0 = *(const float4*)p;
      v1 = *(const float4*)(p + 4);
      v2 = *(const float4*)(p + 32);
      v3 = *(const float4*)(p + 36);
    }
    b0 = pack_bf8(v0, v1);
    b1 = pack_bf8(v2, v3);
  }

#pragma unroll 2
  for (int m = 0; m < NM; ++m) {
    const ushort_t* wt = Wt + (size_t)m * D * D + kb;
    f32x4 acc[4];
#pragma unroll
    for (int ct = 0; ct < 4; ++ct) {
      const ushort_t* wr = wt + (size_t)(16 * ct + (lane & 15)) * D;
      bf16x8 a0 = *(const bf16x8*)wr;
      bf16x8 a1 = *(const bf16x8*)(wr + 32);
      acc[ct] = (f32x4){0.f, 0.f, 0.f, 0.f};
      acc[ct] = __builtin_amdgcn_mfma_f32_16x16x32_bf16(a0, b0, acc[ct], 0, 0, 0);
      acc[ct] = __builtin_amdgcn_mfma_f32_16x16x32_bf16(a1, b1, acc[ct], 0, 0, 0);
    }
    if (node < N) {
      if (m < R8) {
        ushort_t* op = proj + ((size_t)node * R8 + m) * D + 16 * g;
        uint4 w0, w1;
        w0.x = pk2(acc[0][0], acc[0][1]); w0.y = pk2(acc[0][2], acc[0][3]);
        w0.z = pk2(acc[1][0], acc[1][1]); w0.w = pk2(acc[1][2], acc[1][3]);
        w1.x = pk2(acc[2][0], acc[2][1]); w1.y = pk2(acc[2][2], acc[2][3]);
        w1.z = pk2(acc[3][0], acc[3][1]); w1.w = pk2(acc[3][2], acc[3][3]);
        *(uint4*)(op) = w0;
        *(uint4*)(op + 8) = w1;
      } else {
        float* op = out + (size_t)node * D + 4 * g;   // canonical
#pragma unroll
        for (int ct = 0; ct < 4; ++ct) {
          float4 v;
          v.x = acc[ct][0]; v.y = acc[ct][1]; v.z = acc[ct][2]; v.w = acc[ct][3];
          *(float4*)(op + 16 * ct) = v;
        }
      }
    }
  }
}

// Runtime-R variant.
__device__ __forceinline__ void proj_body_rt(const float* __restrict__ feat,
                                             const ushort_t* __restrict__ Wt,
                                             ushort_t* __restrict__ proj,
                                             float* __restrict__ out, int N, int R,
                                             int blk) {
  const int t = threadIdx.x;
  const int lane = t & 63;
  const int wid = t >> 6;
  const int node = blk * 64 + wid * 16 + (lane & 15);
  const int g = lane >> 4;
  const int kb = g * 8;

  bf16x8 b0, b1;
  {
    float4 v0 = make_float4(0.f, 0.f, 0.f, 0.f), v1 = v0, v2 = v0, v3 = v0;
    if (node < N) {
      const float* p = feat + (size_t)node * D + kb;
      v0 = *(const float4*)p;
      v1 = *(const float4*)(p + 4);
      v2 = *(const float4*)(p + 32);
      v3 = *(const float4*)(p + 36);
    }
    b0 = pack_bf8(v0, v1);
    b1 = pack_bf8(v2, v3);
  }

  for (int m = 0; m <= R; ++m) {
    const ushort_t* wt = Wt + (size_t)m * D * D + kb;
    f32x4 acc[4];
#pragma unroll
    for (int ct = 0; ct < 4; ++ct) {
      const ushort_t* wr = wt + (size_t)(16 * ct + (lane & 15)) * D;
      bf16x8 a0 = *(const bf16x8*)wr;
      bf16x8 a1 = *(const bf16x8*)(wr + 32);
      acc[ct] = (f32x4){0.f, 0.f, 0.f, 0.f};
      acc[ct] = __builtin_amdgcn_mfma_f32_16x16x32_bf16(a0, b0, acc[ct], 0, 0, 0);
      acc[ct] = __builtin_amdgcn_mfma_f32_16x16x32_bf16(a1, b1, acc[ct], 0, 0, 0);
    }
    if (node < N) {
      if (m < R) {
        ushort_t* op = proj + ((size_t)node * R + m) * D + 16 * g;
        uint4 w0, w1;
        w0.x = pk2(acc[0][0], acc[0][1]); w0.y = pk2(acc[0][2], acc[0][3]);
        w0.z = pk2(acc[1][0], acc[1][1]); w0.w = pk2(acc[1][2], acc[1][3]);
        w1.x = pk2(acc[2][0], acc[2][1]); w1.y = pk2(acc[2][2], acc[2][3]);
        w1.z = pk2(acc[3][0], acc[3][1]); w1.w = pk2(acc[3][2], acc[3][3]);
        *(uint4*)(op) = w0;
        *(uint4*)(op + 8) = w1;
      } else {
        float* op = out + (size_t)node * D + 4 * g;
#pragma unroll
        for (int ct = 0; ct < 4; ++ct) {
          float4 v;
          v.x = acc[ct][0]; v.y = acc[ct][1]; v.z = acc[ct][2]; v.w = acc[ct][3];
          *(float4*)(op + 16 * ct) = v;
        }
      }
    }
  }
}

// Fused rank+scatter, 8 edges/thread: load all 8 edges' data, issue 8 independent
// atomicAdd returns, then batch the 8 scattered payload stores (compiler's
// fine-grained vmcnt waits pipeline stores against later returns).
__device__ __forceinline__ void scat8_body(const int* __restrict__ esrc,
                                           const int* __restrict__ edst,
                                           const int* __restrict__ etype,
                                           const float* __restrict__ att,
                                           int* __restrict__ deg,
                                           int2* __restrict__ payload,
                                           int* __restrict__ ovcnt,
                                           int4* __restrict__ ovlist,
                                           int E, int sblk) {
  const int base = (sblk * 256 + (int)threadIdx.x) * 8;
  if (base + 7 < E) {
    int4 s0 = *(const int4*)(esrc + base),  s1 = *(const int4*)(esrc + base + 4);
    int4 d0 = *(const int4*)(edst + base),  d1 = *(const int4*)(edst + base + 4);
    int4 t0 = *(const int4*)(etype + base), t1 = *(const int4*)(etype + base + 4);
    float4 a0 = *(const float4*)(att + base), a1 = *(const float4*)(att + base + 4);
    int r0 = atomicAdd(&deg[d0.x], 1);
    int r1 = atomicAdd(&deg[d0.y], 1);
    int r2 = atomicAdd(&deg[d0.z], 1);
    int r3 = atomicAdd(&deg[d0.w], 1);
    int r4 = atomicAdd(&deg[d1.x], 1);
    int r5 = atomicAdd(&deg[d1.y], 1);
    int r6 = atomicAdd(&deg[d1.z], 1);
    int r7 = atomicAdd(&deg[d1.w], 1);
#define EMIT(dn, sv, tv, av, rk)                                                     \
    {                                                                                \
      int2 pay = make_int2((sv) | ((tv) << 24), __float_as_int(av));                 \
      if ((rk) < CAP) payload[(size_t)(dn) * CAP + (rk)] = pay;                      \
      else { int ov = atomicAdd(ovcnt, 1);                                           \
             if (ov < OVCAP) ovlist[ov] = make_int4(pay.x, pay.y, (dn), 0); }        \
    }
    EMIT(d0.x, s0.x, t0.x, a0.x, r0)
    EMIT(d0.y, s0.y, t0.y, a0.y, r1)
    EMIT(d0.z, s0.z, t0.z, a0.z, r2)
    EMIT(d0.w, s0.w, t0.w, a0.w, r3)
    EMIT(d1.x, s1.x, t1.x, a1.x, r4)
    EMIT(d1.y, s1.y, t1.y, a1.y, r5)
    EMIT(d1.z, s1.z, t1.z, a1.z, r6)
    EMIT(d1.w, s1.w, t1.w, a1.w, r7)
#undef EMIT
  } else {
    for (int i = base; i < E; ++i) {
      int dn = edst[i];
      int rk = atomicAdd(&deg[dn], 1);
      int2 pay = make_int2(esrc[i] | (etype[i] << 24), __float_as_int(att[i]));
      if (rk < CAP) payload[(size_t)dn * CAP + rk] = pay;
      else { int ov = atomicAdd(ovcnt, 1); if (ov < OVCAP) ovlist[ov] = make_int4(pay.x, pay.y, dn, 0); }
    }
  }
}

// K2 (R13-proven spatial role partition): blocks [0,PB) proj, [PB,PB+SB) scat8.
__global__ __launch_bounds__(256) void proj_scat(const float* __restrict__ feat,
                                                 const ushort_t* __restrict__ Wt,
                                                 ushort_t* __restrict__ proj,
                                                 float* __restrict__ out,
                                                 const int* __restrict__ esrc,
                                                 const int* __restrict__ edst,
                                                 const int* __restrict__ etype,
                                                 const float* __restrict__ att,
                                                 int* __restrict__ deg,
                                                 int2* __restrict__ payload,
                                                 int* __restrict__ ovcnt,
                                                 int4* __restrict__ ovlist,
                                                 int N, int E, int R, int PB) {
  if ((int)blockIdx.x < PB) {
    if (R == 8)
      proj_body<9>(feat, Wt, proj, out, N, blockIdx.x);
    else
      proj_body_rt(feat, Wt, proj, out, N, R, blockIdx.x);
  } else {
    scat8_body(esrc, edst, etype, att, deg, payload, ovcnt, ovlist, E,
               blockIdx.x - PB);
  }
}

// ---------------- K3: node gather (blocks [0,GB)) || overflow fixup (blocks >= GB) ----------------
__global__ __launch_bounds__(256, 8) void gather_fix(const int* __restrict__ deg,
                                                     const int2* __restrict__ payload,
                                                     const ushort_t* __restrict__ proj,
                                                     const float* __restrict__ hbias,
                                                     float* __restrict__ out, int N,
                                                     int R, int GB,
                                                     const int* __restrict__ ovcnt,
                                                     const int4* __restrict__ ovlist) {
  if ((int)blockIdx.x < GB) {
    const int n = ((int)blockIdx.x * 256 + (int)threadIdx.x) >> 6;
    if (n >= N) return;
    const int lane = threadIdx.x & 63;
    const int sub = lane >> 4;
    const int q = lane & 15;
    const int ac0 = 16 * (q & 3) + 4 * (q >> 2);   // actual col base for chunk q

    const int cnt = min(deg[n], CAP);
    const int2* slots = payload + (size_t)n * CAP;
    float4 acc = make_float4(0.f, 0.f, 0.f, 0.f);
    float sa = 0.f;
    for (int e = sub; e < cnt; e += 4) {
      const int2 pe = slots[e];
      const float a = __int_as_float(pe.y);
      const int src = pe.x & 0x00FFFFFF;
      const int r = ((unsigned)pe.x) >> 24;
      const ushort4 p = *(const ushort4*)(proj + ((size_t)src * R + r) * D + q * 4);
      acc.x = fmaf(a, bf2f(p.x), acc.x);
      acc.y = fmaf(a, bf2f(p.y), acc.y);
      acc.z = fmaf(a, bf2f(p.z), acc.z);
      acc.w = fmaf(a, bf2f(p.w), acc.w);
      sa += a;
    }
#pragma unroll
    for (int m = 16; m < 64; m <<= 1) {
      acc.x += __shfl_xor(acc.x, m);
      acc.y += __shfl_xor(acc.y, m);
      acc.z += __shfl_xor(acc.z, m);
      acc.w += __shfl_xor(acc.w, m);
      sa += __shfl_xor(sa, m);
    }
    if (sub == 0) {
      const float4 hb = *(const float4*)(hbias + ac0);
      float* op = out + (size_t)n * D + ac0;
      float4 cur = *(float4*)op;      // self-loop already there (canonical layout)
      cur.x += acc.x + sa * hb.x;
      cur.y += acc.y + sa * hb.y;
      cur.z += acc.z + sa * hb.z;
      cur.w += acc.w + sa * hb.w;
      *(float4*)op = cur;
    }
  } else {
    const int total = min(*ovcnt, OVCAP) * 16;
    for (int i = ((int)blockIdx.x - GB) * 256 + (int)threadIdx.x; i < total;
         i += 16 * 256) {
      const int idx = i >> 4, q = i & 15;
      const int4 en = ovlist[idx];
      const int src = en.x & 0x00FFFFFF;
      const int r = ((unsigned)en.x) >> 24;
      const float a = __int_as_float(en.y);
      const int ac0 = 16 * (q & 3) + 4 * (q >> 2);
      const ushort4 p = *(const ushort4*)(proj + ((size_t)src * R + r) * D + q * 4);
      const float4 hb = *(const float4*)(hbias + ac0);
      float* op = out + (size_t)en.z * D + ac0;
      unsafeAtomicAdd(op + 0, (bf2f(p.x) + hb.x) * a);
      unsafeAtomicAdd(op + 1, (bf2f(p.y) + hb.y) * a);
      unsafeAtomicAdd(op + 2, (bf2f(p.z) + hb.z) * a);
      unsafeAtomicAdd(op + 3, (bf2f(p.w) + hb.w) * a);
    }
  }
}

// ---------------- fallback path (small ws): fp32 tile GEMM + atomic scatter ----------------
__global__ __launch_bounds__(256, 3) void proj_single(const float* __restrict__ feat,
                                                      const float* __restrict__ W,
                                                      float* __restrict__ outp, int N) {
  __shared__ float sW[64 * 64];
  __shared__ float sF[64 * 132];
  const int t = threadIdx.x;
  const int tileBase = blockIdx.x * 128;

  {
    const float4* Wv = (const float4*)W;
    float4* sWv = (float4*)sW;
    for (int k = t; k < 1024; k += 256) sWv[k] = Wv[k];
  }
  {
    const int row = t >> 1, half = t & 1;
    const int gr = tileBase + row;
    if (gr < N) {
      const float4* src = (const float4*)(feat + (size_t)gr * D + half * 32);
#pragma unroll
      for (int k = 0; k < 8; ++k) {
        float4 v = src[k];
        int i0 = half * 32 + k * 4;
        sF[(i0 + 0) * 132 + row] = v.x;
        sF[(i0 + 1) * 132 + row] = v.y;
        sF[(i0 + 2) * 132 + row] = v.z;
        sF[(i0 + 3) * 132 + row] = v.w;
      }
    } else {
#pragma unroll
      for (int k = 0; k < 8; ++k) {
        int i0 = half * 32 + k * 4;
        sF[(i0 + 0) * 132 + row] = 0.f;
        sF[(i0 + 1) * 132 + row] = 0.f;
        sF[(i0 + 2) * 132 + row] = 0.f;
        sF[(i0 + 3) * 132 + row] = 0.f;
      }
    }
  }
  __syncthreads();

  const int c0 = (t & 15) * 4;
  const int r0 = (t >> 4) * 8;
  float4 acc[8];
#pragma unroll
  for (int rr = 0; rr < 8; ++rr) acc[rr] = make_float4(0.f, 0.f, 0.f, 0.f);

#pragma unroll 8
  for (int i = 0; i < 64; ++i) {
    float4 w  = *(const float4*)&sW[i * 64 + c0];
    float4 a0 = *(const float4*)&sF[i * 132 + r0];
    float4 a1 = *(const float4*)&sF[i * 132 + r0 + 4];
    fma4(acc[0], a0.x, w); fma4(acc[1], a0.y, w);
    fma4(acc[2], a0.z, w); fma4(acc[3], a0.w, w);
    fma4(acc[4], a1.x, w); fma4(acc[5], a1.y, w);
    fma4(acc[6], a1.z, w); fma4(acc[7], a1.w, w);
  }

#pragma unroll
  for (int rr = 0; rr < 8; ++rr) {
    int gn = tileBase + r0 + rr;
    if (gn < N) *(float4*)(outp + (size_t)gn * D + c0) = acc[rr];
  }
}

__global__ __launch_bounds__(256, 8) void edge_scatter(const int* __restrict__ esrc,
                                                       const int* __restrict__ edst,
                                                       const int* __restrict__ etype,
                                                       const float* __restrict__ att,
                                                       const float* __restrict__ proj,
                                                       const float* __restrict__ hbias,
                                                       float* __restrict__ out,
                                                       int E, int N, int relFilter) {
  const int t = blockIdx.x * 256 + threadIdx.x;
  const int wave = t >> 6;
  const int lane = threadIdx.x & 63;
  const int sub = lane >> 4;
  const int q = lane & 15;
  const long e = (long)wave * 4 + sub;
  if (e >= E) return;
  const int r = etype[e];
  if (relFilter >= 0 && r != relFilter) return;
  const int s = esrc[e];
  const int dn = edst[e];
  const float a = att[e];
  const size_t base = (size_t)s * D;
  const float4 hb = ((const float4*)hbias)[q];
  const float4 p = *(const float4*)(proj + base + q * 4);
  float* op = out + (size_t)dn * D + q * 4;
  unsafeAtomicAdd(op + 0, (p.x + hb.x) * a);
  unsafeAtomicAdd(op + 1, (p.y + hb.y) * a);
  unsafeAtomicAdd(op + 2, (p.z + hb.z) * a);
  unsafeAtomicAdd(op + 3, (p.w + hb.w) * a);
}

extern "C" void kernel_launch(void* const* d_in, const int* in_sizes, int n_in,
                              void* d_out, int out_size, void* d_ws, size_t ws_size,
                              hipStream_t stream) {
  const float* feat   = (const float*)d_in[0];
  const int* esrc     = (const int*)d_in[1];
  const int* edst     = (const int*)d_in[2];
  const int* etype    = (const int*)d_in[3];
  const float* att    = (const float*)d_in[4];
  const float* weight = (const float*)d_in[5];
  const float* hbias  = (const float*)d_in[6];
  const float* loopw  = (const float*)d_in[7];
  float* out = (float*)d_out;

  const int N = in_sizes[0] / D;          // 50000
  const int E = in_sizes[1];              // 800000
  const int R = in_sizes[5] / (D * D);    // 8

  const int Npad = (N + 3) & ~3;

  // Workspace: Wt | proj(bf16, node-major) | deg(Npad) | ovcnt | ovlist | payload
  const size_t wtBytes   = (size_t)(R + 1) * D * D * 2;
  const size_t projBytes = (size_t)N * R * D * 2;
  const size_t degOff    = wtBytes + projBytes;
  const size_t ovcntOff  = degOff + (size_t)Npad * 4;
  const size_t ovlistOff = (ovcntOff + 16 + 15) & ~(size_t)15;
  const size_t payOffB   = (ovlistOff + (size_t)OVCAP * 16 + 15) & ~(size_t)15;
  const size_t needSlot  = payOffB + (size_t)N * CAP * 8;

  const int PB = (N + 63) / 64;                       // proj blocks (64 nodes each)
  const int SB = ((E + 7) / 8 + 255) / 256;           // scat8 blocks (2048 edges each)
  const int GB = (N + 3) / 4;                         // gather blocks

  if (ws_size >= needSlot) {
    ushort_t* Wt   = (ushort_t*)d_ws;
    ushort_t* proj = (ushort_t*)((char*)d_ws + wtBytes);
    int* deg       = (int*)((char*)d_ws + degOff);
    int* ovcnt     = (int*)((char*)d_ws + ovcntOff);
    int4* ovlist   = (int4*)((char*)d_ws + ovlistOff);
    int2* payload  = (int2*)((char*)d_ws + payOffB);

    prep<<<(R + 1) + (N + 255) / 256, 256, 0, stream>>>(weight, loopw, Wt, deg,
                                                        ovcnt, R, N);
    proj_scat<<<PB + SB, 256, 0, stream>>>(feat, Wt, proj, out, esrc, edst, etype, att,
                                           deg, payload, ovcnt, ovlist, N, E, R, PB);
    gather_fix<<<GB + 16, 256, 0, stream>>>(deg, payload, proj, hbias, out, N, R, GB,
                                            ovcnt, ovlist);
  } else {
    // Minimal-scratch fallback: needs N*D floats.
    const int tilesN = (N + 127) / 128;
    const int eblocks16 = (E + 15) / 16;
    proj_single<<<tilesN, 256, 0, stream>>>(feat, loopw, out, N);
    for (int r = 0; r < R; ++r) {
      proj_single<<<tilesN, 256, 0, stream>>>(feat, weight + (size_t)r * D * D,
                                              (float*)d_ws, N);
      edge_scatter<<<eblocks16, 256, 0, stream>>>(esrc, edst, etype, att, (float*)d_ws,
                                                  hbias, out, E, N, r);
    }
  }
}